// Round 1
// baseline (219.840 us; speedup 1.0000x reference)
//
#include <hip/hip_runtime.h>
#include <math.h>

#define NQ 8
#define DK 64
#define NB 8
#define NS 1024
#define TS 16   // s-rows per block in attention kernel

// ---------------- Kernel 1: per-token quantum features ----------------
// qf/kf layout: [b*S + s][n*4 + {re0,im0,re1,im1}]  (32 floats per token)
__global__ void feat_kernel(const float* __restrict__ x,
                            const float* __restrict__ theta_q,
                            const float* __restrict__ theta_k,
                            float* __restrict__ qf,
                            float* __restrict__ kf) {
    int tok = blockIdx.x * blockDim.x + threadIdx.x;
    if (tok >= NB * NS) return;
    const float* xr = x + (size_t)tok * DK;

    float q[4 * NQ], k[4 * NQ];
#pragma unroll
    for (int n = 0; n < NQ; ++n) {
        float xn = tanhf(xr[n]);
        float half = xn * 1.57079632679489662f;  // xn * pi/2
        float s, c;
        sincosf(half, &s, &c);
        // ---- Q gate ----
        {
            float phi = theta_q[n * 3 + 0], th = theta_q[n * 3 + 1], om = theta_q[n * 3 + 2];
            float st, ct; sincosf(0.5f * th, &st, &ct);
            float smpo, cmpo; sincosf(0.5f * (phi + om), &smpo, &cmpo);
            float spmo, cpmo; sincosf(0.5f * (phi - om), &spmo, &cpmo);
            float a = ct * c, b = st * s, cc = st * c, d = ct * s;
            q[n * 4 + 0] =  cmpo * a - cpmo * b;
            q[n * 4 + 1] = -smpo * a - spmo * b;
            q[n * 4 + 2] =  cpmo * cc + cmpo * d;
            q[n * 4 + 3] = -spmo * cc + smpo * d;
        }
        // ---- K gate ----
        {
            float phi = theta_k[n * 3 + 0], th = theta_k[n * 3 + 1], om = theta_k[n * 3 + 2];
            float st, ct; sincosf(0.5f * th, &st, &ct);
            float smpo, cmpo; sincosf(0.5f * (phi + om), &smpo, &cmpo);
            float spmo, cpmo; sincosf(0.5f * (phi - om), &spmo, &cpmo);
            float a = ct * c, b = st * s, cc = st * c, d = ct * s;
            k[n * 4 + 0] =  cmpo * a - cpmo * b;
            k[n * 4 + 1] = -smpo * a - spmo * b;
            k[n * 4 + 2] =  cpmo * cc + cmpo * d;
            k[n * 4 + 3] = -spmo * cc + smpo * d;
        }
    }
    float4* qo = (float4*)(qf + (size_t)tok * 32);
    float4* ko = (float4*)(kf + (size_t)tok * 32);
#pragma unroll
    for (int i = 0; i < 8; ++i) {
        qo[i] = make_float4(q[i * 4 + 0], q[i * 4 + 1], q[i * 4 + 2], q[i * 4 + 3]);
        ko[i] = make_float4(k[i * 4 + 0], k[i * 4 + 1], k[i * 4 + 2], k[i * 4 + 3]);
    }
}

// ---------------- Kernel 2: values = x @ W_v^T + b_v ----------------
__global__ void values_kernel(const float* __restrict__ x,
                              const float* __restrict__ Wv,
                              const float* __restrict__ bv,
                              float* __restrict__ values) {
    int t = blockIdx.x * 4 + (threadIdx.x >> 6);
    int d = threadIdx.x & 63;
    if (t >= NB * NS) return;
    const float* xr = x + (size_t)t * DK;
    const float* wr = Wv + (size_t)d * DK;
    float acc = bv[d];
#pragma unroll 8
    for (int j = 0; j < DK; ++j) acc = fmaf(xr[j], wr[j], acc);
    values[(size_t)t * DK + d] = acc;
}

// ---------------- Kernel 3: scores -> softmax -> attn + out ----------------
__global__ __launch_bounds__(256) void attn_kernel(
    const float* __restrict__ qf, const float* __restrict__ kf,
    const float* __restrict__ values,
    float* __restrict__ out, float* __restrict__ attn) {
    __shared__ float s_e[TS][NS];  // 64 KB; holds exp(score) per row

    int blk = blockIdx.x;
    int b = blk >> 6;            // /  (NS/TS)
    int s0 = (blk & 63) * TS;
    int tid = threadIdx.x;
    int r = tid >> 4;            // row 0..15
    int l = tid & 15;            // lane-in-row 0..15
    int srow = s0 + r;
    int swz = (r & 3) << 2;      // XOR swizzle (bits 2..3) to de-alias rows in a wave

    // Q features for this row (broadcast among the 16 lanes of the row group)
    const float4* qp = (const float4*)(qf + ((size_t)(b * NS + srow)) * 32);
    float4 qv[8];
#pragma unroll
    for (int n = 0; n < 8; ++n) qv[n] = qp[n];

    const float* kfb = kf + (size_t)b * NS * 32;

    // Phase 1: scores -> exp -> LDS, accumulate per-thread sum
    float sum = 0.f;
    for (int kki = 0; kki < NS / 16; ++kki) {
        int t = (kki << 4) + l;
        const float4* kp = (const float4*)(kfb + ((size_t)t << 5));
        float core = 1.0f;
#pragma unroll
        for (int n = 0; n < 8; ++n) {
            float4 kq = kp[n];
            float4 q = qv[n];
            float re = fmaf(q.x, kq.x, fmaf(q.y, kq.y, fmaf(q.z, kq.z, q.w * kq.w)));
            float im = fmaf(q.x, kq.y, fmaf(-q.y, kq.x, fmaf(q.z, kq.w, -q.w * kq.z)));
            core *= fmaf(re, re, im * im);
        }
        // score in [0.5, 1] -> no max subtraction needed for softmax
        float e = __expf(fmaf(core, 0.5f, 0.5f));
        s_e[r][t ^ swz] = e;
        sum += e;
    }

    // Reduce sum across the 16 lanes of this row group (within one wave)
#pragma unroll
    for (int m = 1; m < 16; m <<= 1) sum += __shfl_xor(sum, m, 64);
    float inv = 1.0f / sum;

    __syncthreads();

    // Phase 2: write normalized attn row (coalesced float4)
    float* arow = attn + ((size_t)(b * NS + srow)) * NS;
#pragma unroll
    for (int kk = 0; kk < 16; ++kk) {
        int t = (kk << 6) + (l << 2);
        float4 e4 = *(const float4*)&s_e[r][t ^ swz];
        float4 w = make_float4(e4.x * inv, e4.y * inv, e4.z * inv, e4.w * inv);
        *(float4*)&arow[t] = w;
    }

    // Phase 3: out[srow, d0..d0+3] = inv * sum_t e[t] * values[t, d]
    const float* vb = values + (size_t)b * NS * DK;
    int d0 = l << 2;
    float ax = 0.f, ay = 0.f, az = 0.f, aw = 0.f;
    for (int t = 0; t < NS; t += 4) {
        float4 e4 = *(const float4*)&s_e[r][t ^ swz];
        float4 v0 = *(const float4*)&vb[(size_t)(t + 0) * DK + d0];
        float4 v1 = *(const float4*)&vb[(size_t)(t + 1) * DK + d0];
        float4 v2 = *(const float4*)&vb[(size_t)(t + 2) * DK + d0];
        float4 v3 = *(const float4*)&vb[(size_t)(t + 3) * DK + d0];
        ax = fmaf(e4.x, v0.x, fmaf(e4.y, v1.x, fmaf(e4.z, v2.x, fmaf(e4.w, v3.x, ax))));
        ay = fmaf(e4.x, v0.y, fmaf(e4.y, v1.y, fmaf(e4.z, v2.y, fmaf(e4.w, v3.y, ay))));
        az = fmaf(e4.x, v0.z, fmaf(e4.y, v1.z, fmaf(e4.z, v2.z, fmaf(e4.w, v3.z, az))));
        aw = fmaf(e4.x, v0.w, fmaf(e4.y, v1.w, fmaf(e4.z, v2.w, fmaf(e4.w, v3.w, aw))));
    }
    float4 o = make_float4(ax * inv, ay * inv, az * inv, aw * inv);
    *(float4*)&out[((size_t)(b * NS + srow)) * DK + d0] = o;
}

extern "C" void kernel_launch(void* const* d_in, const int* in_sizes, int n_in,
                              void* d_out, int out_size, void* d_ws, size_t ws_size,
                              hipStream_t stream) {
    const float* x       = (const float*)d_in[0];
    const float* theta_q = (const float*)d_in[1];
    const float* theta_k = (const float*)d_in[2];
    const float* W_v     = (const float*)d_in[3];
    const float* b_v     = (const float*)d_in[4];

    float* out  = (float*)d_out;                       // [8,1024,64]
    float* attn = (float*)d_out + (size_t)NB * NS * DK; // [8,1024,1024]

    float* qf     = (float*)d_ws;                       // 8192*32 floats
    float* kfeat  = qf + (size_t)NB * NS * 32;          // 8192*32 floats
    float* values = kfeat + (size_t)NB * NS * 32;       // 8192*64 floats

    feat_kernel<<<(NB * NS + 255) / 256, 256, 0, stream>>>(x, theta_q, theta_k, qf, kfeat);
    values_kernel<<<NB * NS / 4, 256, 0, stream>>>(x, W_v, b_v, values);
    attn_kernel<<<NB * (NS / TS), 256, 0, stream>>>(qf, kfeat, values, out, attn);
}

// Round 3
// 114.955 us; speedup vs baseline: 1.9124x; 1.9124x over previous
//
#include <hip/hip_runtime.h>
#include <math.h>

#define NQ 8
#define DK 64
#define NB 8
#define NS 1024
#define RB 8            // rows per block in attn kernel
#define TILE 64         // t-tokens per tile
#define NT (NS / TILE)  // 16 tiles

// ---------------- Kernel 1: per-token quantum features ----------------
// one thread per (token, qubit). qf/kf layout: [tok][n*4 + {re0,im0,re1,im1}]
__global__ void feat_kernel(const float* __restrict__ x,
                            const float* __restrict__ theta_q,
                            const float* __restrict__ theta_k,
                            float* __restrict__ qf,
                            float* __restrict__ kf) {
    int gid = blockIdx.x * blockDim.x + threadIdx.x;
    if (gid >= NB * NS * NQ) return;
    int tok = gid >> 3;
    int n = gid & 7;

    float xin = x[(size_t)tok * DK + n];
    float ex = __expf(2.0f * xin);               // fast tanh
    float xn = 1.0f - 2.0f / (ex + 1.0f);
    float half = xn * 1.57079632679489662f;      // xn * pi/2
    float s, c;
    __sincosf(half, &s, &c);

    {
        float phi = theta_q[n * 3 + 0], th = theta_q[n * 3 + 1], om = theta_q[n * 3 + 2];
        float st, ct; __sincosf(0.5f * th, &st, &ct);
        float smpo, cmpo; __sincosf(0.5f * (phi + om), &smpo, &cmpo);
        float spmo, cpmo; __sincosf(0.5f * (phi - om), &spmo, &cpmo);
        float a = ct * c, b = st * s, cc = st * c, d = ct * s;
        float4 o = make_float4( cmpo * a - cpmo * b,
                               -smpo * a - spmo * b,
                                cpmo * cc + cmpo * d,
                               -spmo * cc + smpo * d);
        *(float4*)&qf[(size_t)tok * 32 + n * 4] = o;
    }
    {
        float phi = theta_k[n * 3 + 0], th = theta_k[n * 3 + 1], om = theta_k[n * 3 + 2];
        float st, ct; __sincosf(0.5f * th, &st, &ct);
        float smpo, cmpo; __sincosf(0.5f * (phi + om), &smpo, &cmpo);
        float spmo, cpmo; __sincosf(0.5f * (phi - om), &spmo, &cpmo);
        float a = ct * c, b = st * s, cc = st * c, d = ct * s;
        float4 o = make_float4( cmpo * a - cpmo * b,
                               -smpo * a - spmo * b,
                                cpmo * cc + cmpo * d,
                               -spmo * cc + smpo * d);
        *(float4*)&kf[(size_t)tok * 32 + n * 4] = o;
    }
}

// ---------------- Kernel 2: values = x @ W_v^T + b_v ----------------
__global__ void values_kernel(const float* __restrict__ x,
                              const float* __restrict__ Wv,
                              const float* __restrict__ bv,
                              float* __restrict__ values) {
    int t = blockIdx.x * 4 + (threadIdx.x >> 6);
    int d = threadIdx.x & 63;
    if (t >= NB * NS) return;
    const float4* xr = (const float4*)(x + (size_t)t * DK);
    const float4* wr = (const float4*)(Wv + (size_t)d * DK);
    float acc = bv[d];
#pragma unroll
    for (int j = 0; j < DK / 4; ++j) {
        float4 xv = xr[j], wv = wr[j];
        acc = fmaf(xv.x, wv.x, acc);
        acc = fmaf(xv.y, wv.y, acc);
        acc = fmaf(xv.z, wv.z, acc);
        acc = fmaf(xv.w, wv.w, acc);
    }
    values[(size_t)t * DK + d] = acc;
}

// ---------------- Kernel A: tiled scores + unnormalized attn + PV ----------------
// 1024 blocks x 256 threads; block owns RB=8 rows; loops over 16 k/v tiles of 64.
// All LDS write->read dependences cross __syncthreads.
__global__ __launch_bounds__(256) void attn_kernel(
    const float* __restrict__ qf, const float* __restrict__ kf,
    const float* __restrict__ values,
    float* __restrict__ out, float* __restrict__ attn) {
    __shared__ float k_lds[TILE * 32];      // 8 KB, XOR-swizzled
    __shared__ float e_lds[RB][TILE];       // 2 KB
    __shared__ float red_lds[16][64];       // 4 KB
    __shared__ float inv_lds[RB];

    int tid = threadIdx.x;
    int blk = blockIdx.x;
    int gr0 = blk * RB;        // global row base (= b*NS + s0)
    int b = gr0 >> 10;
    int w = tid >> 6, lane = tid & 63;
    int tg = tid >> 4, dg = tid & 15;

    const float* kfb = kf + (size_t)b * NS * 32;
    const float* vb  = values + (size_t)b * NS * DK;

    float acc[RB][4];
#pragma unroll
    for (int r = 0; r < RB; ++r) { acc[r][0] = acc[r][1] = acc[r][2] = acc[r][3] = 0.f; }
    float ssum0 = 0.f, ssum1 = 0.f;

    for (int tile = 0; tile < NT; ++tile) {
        int t0 = tile * TILE;
        // ---- stage k tile (coalesced global -> swizzled LDS) ----
#pragma unroll
        for (int s = 0; s < 2; ++s) {
            int j = s * 256 + tid;            // 512 float4s total
            int t = j >> 3, c = j & 7;
            float4 kv = *(const float4*)(kfb + ((size_t)(t0 + t)) * 32 + c * 4);
            int dst = (t * 32 + c * 4) ^ ((t & 7) << 2);
            *(float4*)&k_lds[dst] = kv;
        }
        __syncthreads();

        // ---- scores: lane = token, wave w handles rows 2w, 2w+1 ----
        float kq[32];
#pragma unroll
        for (int c = 0; c < 8; ++c)
            *(float4*)&kq[c * 4] =
                *(const float4*)&k_lds[(lane * 32 + c * 4) ^ ((lane & 7) << 2)];
#pragma unroll
        for (int r2 = 0; r2 < 2; ++r2) {
            int row = w * 2 + r2;
            int grow = gr0 + row;
            const float4* qp = (const float4*)(qf + (size_t)grow * 32);
            float core = 1.f;
#pragma unroll
            for (int n = 0; n < 8; ++n) {
                float4 q = qp[n];
                float k0 = kq[n*4+0], k1 = kq[n*4+1], k2 = kq[n*4+2], k3 = kq[n*4+3];
                float re = fmaf(q.x, k0, fmaf(q.y, k1, fmaf(q.z, k2, q.w * k3)));
                float im = fmaf(q.x, k1, fmaf(-q.y, k0, fmaf(q.z, k3, -q.w * k2)));
                core *= fmaf(re, re, im * im);
            }
            float e = __expf(fmaf(core, 0.5f, 0.5f));  // score in [0.5,1]
            e_lds[row][lane] = e;
            if (r2 == 0) ssum0 += e; else ssum1 += e;
            attn[(size_t)grow * NS + t0 + lane] = e;   // unnormalized
        }
        __syncthreads();

        // ---- PV: thread (tg,dg) owns t = t0+tg*4..+3, d = dg*4..+3 ----
        {
            const float* vp = vb + ((size_t)(t0 + tg * 4)) * DK + dg * 4;
            float4 v0 = *(const float4*)(vp);
            float4 v1 = *(const float4*)(vp + DK);
            float4 v2 = *(const float4*)(vp + 2 * DK);
            float4 v3 = *(const float4*)(vp + 3 * DK);
#pragma unroll
            for (int r = 0; r < RB; ++r) {
                float4 e4 = *(const float4*)&e_lds[r][tg * 4];
                acc[r][0] = fmaf(e4.x, v0.x, fmaf(e4.y, v1.x, fmaf(e4.z, v2.x, fmaf(e4.w, v3.x, acc[r][0]))));
                acc[r][1] = fmaf(e4.x, v0.y, fmaf(e4.y, v1.y, fmaf(e4.z, v2.y, fmaf(e4.w, v3.y, acc[r][1]))));
                acc[r][2] = fmaf(e4.x, v0.z, fmaf(e4.y, v1.z, fmaf(e4.z, v2.z, fmaf(e4.w, v3.z, acc[r][2]))));
                acc[r][3] = fmaf(e4.x, v0.w, fmaf(e4.y, v1.w, fmaf(e4.z, v2.w, fmaf(e4.w, v3.w, acc[r][3]))));
            }
        }
        __syncthreads();
    }

    // ---- row sums -> inv (wave w owns rows 2w, 2w+1) ----
#pragma unroll
    for (int m = 1; m < 64; m <<= 1) {
        ssum0 += __shfl_xor(ssum0, m, 64);
        ssum1 += __shfl_xor(ssum1, m, 64);
    }
    if (lane == 0) {
        inv_lds[w * 2 + 0] = 1.f / ssum0;
        inv_lds[w * 2 + 1] = 1.f / ssum1;
    }
    __syncthreads();

    // ---- out reduce: combine 16 t-group partials per row ----
#pragma unroll
    for (int r = 0; r < RB; ++r) {
        *(float4*)&red_lds[tg][dg * 4] = make_float4(acc[r][0], acc[r][1], acc[r][2], acc[r][3]);
        __syncthreads();
        if (tid < 64) {
            float o = 0.f;
#pragma unroll
            for (int g = 0; g < 16; ++g) o += red_lds[g][tid];
            out[((size_t)(gr0 + r)) * DK + tid] = o * inv_lds[r];
        }
        __syncthreads();
    }
}

// ---------------- Kernel B: per-row renormalize attn in place ----------------
__global__ __launch_bounds__(256) void rescale_kernel(float* __restrict__ attn) {
    __shared__ float wsum[4];
    int row = blockIdx.x;
    int tid = threadIdx.x;
    float* p = attn + (size_t)row * NS + tid * 4;
    float4 v = *(float4*)p;
    float s = v.x + v.y + v.z + v.w;
#pragma unroll
    for (int m = 1; m < 64; m <<= 1) s += __shfl_xor(s, m, 64);
    if ((tid & 63) == 0) wsum[tid >> 6] = s;
    __syncthreads();
    float inv = 1.f / (wsum[0] + wsum[1] + wsum[2] + wsum[3]);
    v.x *= inv; v.y *= inv; v.z *= inv; v.w *= inv;
    *(float4*)p = v;
}

extern "C" void kernel_launch(void* const* d_in, const int* in_sizes, int n_in,
                              void* d_out, int out_size, void* d_ws, size_t ws_size,
                              hipStream_t stream) {
    const float* x       = (const float*)d_in[0];
    const float* theta_q = (const float*)d_in[1];
    const float* theta_k = (const float*)d_in[2];
    const float* W_v     = (const float*)d_in[3];
    const float* b_v     = (const float*)d_in[4];

    float* out  = (float*)d_out;                        // [8,1024,64]
    float* attn = (float*)d_out + (size_t)NB * NS * DK; // [8,1024,1024]

    float* qf     = (float*)d_ws;                       // 8192*32 floats (1 MB)
    float* kfeat  = qf + (size_t)NB * NS * 32;          // 8192*32 floats (1 MB)
    float* values = kfeat + (size_t)NB * NS * 32;       // 8192*64 floats (2 MB)

    feat_kernel<<<(NB * NS * NQ + 255) / 256, 256, 0, stream>>>(x, theta_q, theta_k, qf, kfeat);
    values_kernel<<<NB * NS / 4, 256, 0, stream>>>(x, W_v, b_v, values);
    attn_kernel<<<NB * NS / RB, 256, 0, stream>>>(qf, kfeat, values, out, attn);
    rescale_kernel<<<NB * NS, 256, 0, stream>>>(attn);
}

// Round 4
// 73.506 us; speedup vs baseline: 2.9908x; 1.5639x over previous
//
#include <hip/hip_runtime.h>
#include <math.h>

#define NQ 8
#define DK 64
#define NB 8
#define NS 1024
#define RB 8            // rows per block in attn kernel

// ---------------- Kernel 1: per-token quantum features ----------------
// one thread per (token, qubit). qf/kf layout: [tok][n*4 + {re0,im0,re1,im1}]
__global__ void feat_kernel(const float* __restrict__ x,
                            const float* __restrict__ theta_q,
                            const float* __restrict__ theta_k,
                            float* __restrict__ qf,
                            float* __restrict__ kf) {
    int gid = blockIdx.x * blockDim.x + threadIdx.x;
    if (gid >= NB * NS * NQ) return;
    int tok = gid >> 3;
    int n = gid & 7;

    float xin = x[(size_t)tok * DK + n];
    float ex = __expf(2.0f * xin);               // fast tanh
    float xn = 1.0f - 2.0f / (ex + 1.0f);
    float half = xn * 1.57079632679489662f;      // xn * pi/2
    float s, c;
    __sincosf(half, &s, &c);

    {
        float phi = theta_q[n * 3 + 0], th = theta_q[n * 3 + 1], om = theta_q[n * 3 + 2];
        float st, ct; __sincosf(0.5f * th, &st, &ct);
        float smpo, cmpo; __sincosf(0.5f * (phi + om), &smpo, &cmpo);
        float spmo, cpmo; __sincosf(0.5f * (phi - om), &spmo, &cpmo);
        float a = ct * c, b = st * s, cc = st * c, d = ct * s;
        float4 o = make_float4( cmpo * a - cpmo * b,
                               -smpo * a - spmo * b,
                                cpmo * cc + cmpo * d,
                               -spmo * cc + smpo * d);
        *(float4*)&qf[(size_t)tok * 32 + n * 4] = o;
    }
    {
        float phi = theta_k[n * 3 + 0], th = theta_k[n * 3 + 1], om = theta_k[n * 3 + 2];
        float st, ct; __sincosf(0.5f * th, &st, &ct);
        float smpo, cmpo; __sincosf(0.5f * (phi + om), &smpo, &cmpo);
        float spmo, cpmo; __sincosf(0.5f * (phi - om), &spmo, &cpmo);
        float a = ct * c, b = st * s, cc = st * c, d = ct * s;
        float4 o = make_float4( cmpo * a - cpmo * b,
                               -smpo * a - spmo * b,
                                cpmo * cc + cmpo * d,
                               -spmo * cc + smpo * d);
        *(float4*)&kf[(size_t)tok * 32 + n * 4] = o;
    }
}

// ---------------- Kernel 2: values = x @ W_v^T + b_v ----------------
__global__ void values_kernel(const float* __restrict__ x,
                              const float* __restrict__ Wv,
                              const float* __restrict__ bv,
                              float* __restrict__ values) {
    int t = blockIdx.x * 4 + (threadIdx.x >> 6);
    int d = threadIdx.x & 63;
    if (t >= NB * NS) return;
    const float4* xr = (const float4*)(x + (size_t)t * DK);
    const float4* wr = (const float4*)(Wv + (size_t)d * DK);
    float acc = bv[d];
#pragma unroll
    for (int j = 0; j < DK / 4; ++j) {
        float4 xv = xr[j], wv = wr[j];
        acc = fmaf(xv.x, wv.x, acc);
        acc = fmaf(xv.y, wv.y, acc);
        acc = fmaf(xv.z, wv.z, acc);
        acc = fmaf(xv.w, wv.w, acc);
    }
    values[(size_t)t * DK + d] = acc;
}

// ---------------- Kernel 3: fused scores -> softmax -> attn + PV ----------------
// 1024 blocks x 256 threads. Block owns 8 rows of one batch.
// Phase 1: lane=token, computes 8 rows' e -> e_lds[8][1024], per-lane row sums.
// Phase 2: normalized attn write. Phase 3: PV from e_lds, out-reduce.
__global__ __launch_bounds__(256, 4) void attn_kernel(
    const float* __restrict__ qf, const float* __restrict__ kf,
    const float* __restrict__ values,
    float* __restrict__ out, float* __restrict__ attn) {
    __shared__ float e_lds[RB][NS];       // 32 KB
    __shared__ float q_lds[RB][32];       // 1 KB
    __shared__ float red_lds[16][64];     // 4 KB
    __shared__ float sums_lds[4][RB];
    __shared__ float inv_lds[RB];

    int tid = threadIdx.x;
    int gr0 = blockIdx.x * RB;            // global row base (= b*NS + s0)
    int b = gr0 >> 10;
    int w = tid >> 6, lane = tid & 63;

    // stage Q for the block's 8 rows
    if (tid < RB * 8) {
        int r = tid >> 3, c = tid & 7;
        *(float4*)&q_lds[r][c * 4] = *(const float4*)&qf[((size_t)(gr0 + r)) * 32 + c * 4];
    }
    __syncthreads();

    const float* kfb = kf + (size_t)b * NS * 32;

    // ---- Phase 1: scores + exp for all 1024 tokens x 8 rows ----
    float sums[RB];
#pragma unroll
    for (int r = 0; r < RB; ++r) sums[r] = 0.f;

#pragma unroll
    for (int kk = 0; kk < 4; ++kk) {
        int t = kk * 256 + tid;
        const float4* kp = (const float4*)(kfb + ((size_t)t << 5));
        float kq[32];
#pragma unroll
        for (int c = 0; c < 8; ++c) *(float4*)&kq[c * 4] = kp[c];
#pragma unroll
        for (int r = 0; r < RB; ++r) {
            float m[8];
#pragma unroll
            for (int n = 0; n < 8; ++n) {
                float4 q = *(const float4*)&q_lds[r][n * 4];   // wave-uniform broadcast
                float k0 = kq[n*4+0], k1 = kq[n*4+1], k2 = kq[n*4+2], k3 = kq[n*4+3];
                float re = fmaf(q.x, k0, fmaf(q.y, k1, fmaf(q.z, k2, q.w * k3)));
                float im = fmaf(q.x, k1, fmaf(-q.y, k0, fmaf(q.z, k3, -q.w * k2)));
                m[n] = fmaf(re, re, im * im);
            }
            float core = ((m[0]*m[1]) * (m[2]*m[3])) * ((m[4]*m[5]) * (m[6]*m[7]));
            float e = __expf(fmaf(core, 0.5f, 0.5f));  // score in [0.5,1] -> no max needed
            e_lds[r][t] = e;
            sums[r] += e;
        }
    }

    // wave-level row-sum reduce, then cross-wave combine
#pragma unroll
    for (int r = 0; r < RB; ++r) {
#pragma unroll
        for (int msk = 1; msk < 64; msk <<= 1) sums[r] += __shfl_xor(sums[r], msk, 64);
    }
    if (lane == 0) {
#pragma unroll
        for (int r = 0; r < RB; ++r) sums_lds[w][r] = sums[r];
    }
    __syncthreads();
    if (tid < RB)
        inv_lds[tid] = 1.f / (sums_lds[0][tid] + sums_lds[1][tid] + sums_lds[2][tid] + sums_lds[3][tid]);
    __syncthreads();

    float inv[RB];
#pragma unroll
    for (int r = 0; r < RB; ++r) inv[r] = inv_lds[r];

    // ---- Phase 2: write normalized attn (coalesced float4) ----
    float* ab = attn + (size_t)gr0 * NS;
#pragma unroll
    for (int r = 0; r < RB; ++r) {
        float4 e4 = *(const float4*)&e_lds[r][tid * 4];
        float iv = inv[r];
        *(float4*)&ab[(size_t)r * NS + tid * 4] =
            make_float4(e4.x * iv, e4.y * iv, e4.z * iv, e4.w * iv);
    }

    // ---- Phase 3: PV. thread (tg,dg): tokens tg*4.. step 64, dims dg*4..+3 ----
    int tg = tid >> 4, dg = tid & 15;
    const float* vb = values + (size_t)b * NS * DK;
    float acc[RB][4];
#pragma unroll
    for (int r = 0; r < RB; ++r) { acc[r][0] = acc[r][1] = acc[r][2] = acc[r][3] = 0.f; }

    for (int jj = 0; jj < 16; ++jj) {
        int t = jj * 64 + tg * 4;
        const float* vp = vb + (size_t)t * DK + dg * 4;
        float4 v0 = *(const float4*)(vp);
        float4 v1 = *(const float4*)(vp + DK);
        float4 v2 = *(const float4*)(vp + 2 * DK);
        float4 v3 = *(const float4*)(vp + 3 * DK);
#pragma unroll
        for (int r = 0; r < RB; ++r) {
            float4 e4 = *(const float4*)&e_lds[r][t];
            acc[r][0] = fmaf(e4.x, v0.x, fmaf(e4.y, v1.x, fmaf(e4.z, v2.x, fmaf(e4.w, v3.x, acc[r][0]))));
            acc[r][1] = fmaf(e4.x, v0.y, fmaf(e4.y, v1.y, fmaf(e4.z, v2.y, fmaf(e4.w, v3.y, acc[r][1]))));
            acc[r][2] = fmaf(e4.x, v0.z, fmaf(e4.y, v1.z, fmaf(e4.z, v2.z, fmaf(e4.w, v3.z, acc[r][2]))));
            acc[r][3] = fmaf(e4.x, v0.w, fmaf(e4.y, v1.w, fmaf(e4.z, v2.w, fmaf(e4.w, v3.w, acc[r][3]))));
        }
    }

    // ---- out reduce: combine 16 t-group partials per row ----
#pragma unroll
    for (int r = 0; r < RB; ++r) {
        __syncthreads();
        *(float4*)&red_lds[tg][dg * 4] = make_float4(acc[r][0], acc[r][1], acc[r][2], acc[r][3]);
        __syncthreads();
        if (tid < 64) {
            float o = 0.f;
#pragma unroll
            for (int g = 0; g < 16; ++g) o += red_lds[g][tid];
            out[((size_t)(gr0 + r)) * DK + tid] = o * inv[r];
        }
    }
}

extern "C" void kernel_launch(void* const* d_in, const int* in_sizes, int n_in,
                              void* d_out, int out_size, void* d_ws, size_t ws_size,
                              hipStream_t stream) {
    const float* x       = (const float*)d_in[0];
    const float* theta_q = (const float*)d_in[1];
    const float* theta_k = (const float*)d_in[2];
    const float* W_v     = (const float*)d_in[3];
    const float* b_v     = (const float*)d_in[4];

    float* out  = (float*)d_out;                        // [8,1024,64]
    float* attn = (float*)d_out + (size_t)NB * NS * DK; // [8,1024,1024]

    float* qf     = (float*)d_ws;                       // 8192*32 floats (1 MB)
    float* kfeat  = qf + (size_t)NB * NS * 32;          // 8192*32 floats (1 MB)
    float* values = kfeat + (size_t)NB * NS * 32;       // 8192*64 floats (2 MB)

    feat_kernel<<<(NB * NS * NQ + 255) / 256, 256, 0, stream>>>(x, theta_q, theta_k, qf, kfeat);
    values_kernel<<<NB * NS / 4, 256, 0, stream>>>(x, W_v, b_v, values);
    attn_kernel<<<NB * NS / RB, 256, 0, stream>>>(qf, kfeat, values, out, attn);
}